// Round 1
// 997.334 us; speedup vs baseline: 1.0084x; 1.0084x over previous
//
#include <hip/hip_runtime.h>
#include <hip/hip_bf16.h>
#include <math.h>

// Problem constants (from reference): B=64, C=768, H=W=64 (HW=4096), E=16, TOP_K=2
#define B_ 64
#define C_ 768
#define HW_ 4096
#define E_ 16
#define NOISE_EPS_ 0.01f

// rows (b,c pairs) per block in the pooling kernel; must divide C_ (16 | 768)
#define ROWS_ 16

typedef float f32x4 __attribute__((ext_vector_type(4)));

// ---------------------------------------------------------------------------
// K1: weighted spatial mean.  pooled[b,c] = (1/HW) * sum_hw x[b,c,hw] * (1 + m[b,hw]*cw + cb)
//
// One block of 256 threads handles ROWS_=16 consecutive (b,c) rows (all same b,
// since 16 | 768).  The m-derived weight for each thread's 16 fixed hw-positions
// is computed ONCE into registers, then 16 x-rows (256 KB) stream through it via
// nontemporal float4 loads.  16 independent accumulators give deep ILP; the
// shuffle-reduce tail is paid once per 256 KB instead of once per 16 KB.
// ---------------------------------------------------------------------------
__global__ __launch_bounds__(256) void pool_kernel(
    const float* __restrict__ x, const float* __restrict__ m,
    const float* __restrict__ conv_w, const float* __restrict__ conv_b,
    float* __restrict__ pooled)
{
    const int g    = blockIdx.x;          // 0 .. B*C/ROWS_ - 1  (3072)
    const int row0 = g * ROWS_;           // first (b,c) row of this block
    const int b    = row0 / C_;           // same b for all ROWS_ rows (16 | 768)
    const int t    = threadIdx.x;

    const float cw = conv_w[0];
    const float w0 = 1.0f + conv_b[0];    // weight = m*cw + (1+cb)

    // --- weights: computed once, live in 16 VGPRs ---
    const f32x4* mp = (const f32x4*)(m + (size_t)b * HW_);
    f32x4 wv[4];
#pragma unroll
    for (int k = 0; k < 4; ++k) {
        const f32x4 mv = mp[t + k * 256];
        wv[k].x = fmaf(mv.x, cw, w0);
        wv[k].y = fmaf(mv.y, cw, w0);
        wv[k].z = fmaf(mv.z, cw, w0);
        wv[k].w = fmaf(mv.w, cw, w0);
    }

    // --- stream 16 rows of x through the cached weights ---
    const f32x4* xp = (const f32x4*)(x + (size_t)row0 * HW_);
    float rsum[ROWS_];
#pragma unroll
    for (int r = 0; r < ROWS_; ++r) rsum[r] = 0.0f;

#pragma unroll
    for (int r = 0; r < ROWS_; ++r) {
        float s = 0.0f;
#pragma unroll
        for (int k = 0; k < 4; ++k) {
            const f32x4 xv = __builtin_nontemporal_load(xp + (size_t)r * 1024 + t + k * 256);
            s += xv.x * wv[k].x;
            s += xv.y * wv[k].y;
            s += xv.z * wv[k].z;
            s += xv.w * wv[k].w;
        }
        rsum[r] = s;
    }

    // --- wave (64-lane) butterfly reduce, 16 independent chains interleave ---
#pragma unroll
    for (int off = 32; off > 0; off >>= 1) {
#pragma unroll
        for (int r = 0; r < ROWS_; ++r)
            rsum[r] += __shfl_down(rsum[r], off, 64);
    }

    __shared__ float red[4][ROWS_];
    const int wid  = t >> 6;
    const int lane = t & 63;
    if (lane == 0) {
#pragma unroll
        for (int r = 0; r < ROWS_; ++r) red[wid][r] = rsum[r];
    }
    __syncthreads();
    if (t < ROWS_)
        pooled[row0 + t] =
            (red[0][t] + red[1][t] + red[2][t] + red[3][t]) * (1.0f / (float)HW_);
}

// ---------------------------------------------------------------------------
// K2: per-row gating.  One block per b (256 threads).
//   clean  = pooled @ wg.T + bg
//   stddev = softplus(pooled @ wn.T + bn) + eps
//   logits = clean + z * stddev
//   top-2 -> softmax -> scatter into gates row of d_out
// ---------------------------------------------------------------------------
__global__ __launch_bounds__(256) void gate_kernel(
    const float* __restrict__ pooled, const float* __restrict__ z,
    const float* __restrict__ wg, const float* __restrict__ bg,
    const float* __restrict__ wn, const float* __restrict__ bn,
    float* __restrict__ out)
{
    const int b = blockIdx.x;
    const int t = threadIdx.x;

    __shared__ float sp[C_];
    __shared__ float lg[E_];

    for (int i = t; i < C_; i += 256) sp[i] = pooled[b * C_ + i];
    __syncthreads();

    const int e = t >> 4;   // expert 0..15
    const int j = t & 15;   // 16 lanes per expert

    float pg = 0.0f, pn = 0.0f;
    for (int c = j; c < C_; c += 16) {
        const float p = sp[c];
        pg = fmaf(p, wg[e * C_ + c], pg);
        pn = fmaf(p, wn[e * C_ + c], pn);
    }
    // reduce across the 16 lanes of each expert-group (groups are contiguous lanes)
#pragma unroll
    for (int off = 8; off > 0; off >>= 1) {
        pg += __shfl_down(pg, off, 16);
        pn += __shfl_down(pn, off, 16);
    }
    if (j == 0) {
        const float clean = pg + bg[e];
        const float npre  = pn + bn[e];
        // stable softplus: max(x,0) + log1p(exp(-|x|))
        const float splus = fmaxf(npre, 0.0f) + log1pf(expf(-fabsf(npre)));
        lg[e] = clean + z[b * E_ + e] * (splus + NOISE_EPS_);
    }
    __syncthreads();

    if (t == 0) {
        // top-2 with tie-break on lowest index (matches jax.lax.top_k)
        float l0 = -INFINITY, l1 = -INFINITY;
        int   i0 = 0,         i1 = 0;
#pragma unroll
        for (int k = 0; k < E_; ++k) {
            const float v = lg[k];
            if (v > l0)      { l1 = l0; i1 = i0; l0 = v; i0 = k; }
            else if (v > l1) { l1 = v;  i1 = k; }
        }
        const float g0 = 1.0f / (1.0f + expf(l1 - l0));
        const float g1 = 1.0f - g0;
        float* row = out + b * E_;
#pragma unroll
        for (int k = 0; k < E_; ++k)
            row[k] = (k == i0) ? g0 : ((k == i1) ? g1 : 0.0f);
    }
}

// ---------------------------------------------------------------------------
// K3: load[e] = sum_b gates[b,e]   (deterministic, no atomics)
// ---------------------------------------------------------------------------
__global__ void load_kernel(const float* __restrict__ gates, float* __restrict__ load)
{
    const int e = threadIdx.x;
    if (e < E_) {
        float s = 0.0f;
        for (int b = 0; b < B_; ++b) s += gates[b * E_ + e];
        load[e] = s;
    }
}

extern "C" void kernel_launch(void* const* d_in, const int* in_sizes, int n_in,
                              void* d_out, int out_size, void* d_ws, size_t ws_size,
                              hipStream_t stream)
{
    const float* x      = (const float*)d_in[0];
    const float* m      = (const float*)d_in[1];
    const float* z      = (const float*)d_in[2];
    const float* conv_w = (const float*)d_in[3];
    const float* conv_b = (const float*)d_in[4];
    const float* wg     = (const float*)d_in[5];
    const float* bg     = (const float*)d_in[6];
    const float* wn     = (const float*)d_in[7];
    const float* bn     = (const float*)d_in[8];

    float* out    = (float*)d_out;              // [B*E gates][E load] = 1040 floats
    float* pooled = (float*)d_ws;               // B*C floats = 192 KB scratch

    pool_kernel<<<(B_ * C_) / ROWS_, 256, 0, stream>>>(x, m, conv_w, conv_b, pooled);
    gate_kernel<<<B_, 256, 0, stream>>>(pooled, z, wg, bg, wn, bn, out);
    load_kernel<<<1, 64, 0, stream>>>(out, out + B_ * E_);
}